// Round 3
// baseline (2097.395 us; speedup 1.0000x reference)
//
#include <hip/hip_runtime.h>

#define SS 1024
#define BB 2048
#define NT 128     // 2 waves/block: wave0 = fwd pair (f0,f1), wave1 = bwd pair (b0,b1)
#define GRID 2048  // 1 batch/block; 8 blocks/CU -> 4 waves/SIMD @ 128 VGPR

typedef unsigned int u32;
typedef unsigned short u16;
typedef _Float16 half2v __attribute__((ext_vector_type(2)));
typedef __fp16 fp16x2 __attribute__((ext_vector_type(2)));
typedef int int2v __attribute__((ext_vector_type(2)));

#define L2E 1.4426950408889634f

// Compile-time-only fence for intra-wave LDS ordering (per-wave DS in-order).
#define CFENCE() asm volatile("" ::: "memory")
// Cross-wave handoff: drain own DS ops, then workgroup barrier. vmcnt NOT
// drained, so the x prefetch stays in flight across the barrier.
#define BARRIER() asm volatile("s_waitcnt lgkmcnt(0)\n\ts_barrier" ::: "memory")

// DPP-based add of a cross-lane shifted copy (pure VALU pipe, no LGKM).
#define DPPADD(v, ctrl, rm)                                                   \
  do {                                                                        \
    int _t = __builtin_amdgcn_update_dpp(0, __float_as_int(v), (ctrl), (rm),  \
                                         0xf, true);                          \
    (v) += __int_as_float(_t);                                                \
  } while (0)

// ---------- helpers ----------
__device__ __forceinline__ u16 f2bf(float f) {  // RNE fp32->bf16
  u32 u = __float_as_uint(f);
  return (u16)((u + 0x7fffu + ((u >> 16) & 1u)) >> 16);
}
template<bool BFM>
__device__ __forceinline__ float ldin(const void* p, int i) {
  if (BFM) { u16 v = ((const u16*)p)[i]; return __uint_as_float(((u32)v) << 16); }
  return ((const float*)p)[i];
}
__device__ __forceinline__ u32 packrtz(float lo, float hi) {
#if __has_builtin(__builtin_amdgcn_cvt_pkrtz)
  fp16x2 h = __builtin_amdgcn_cvt_pkrtz(lo, hi);
  return __builtin_bit_cast(u32, h);
#else
  _Float16 ha = (_Float16)lo, hb = (_Float16)hi;
  return (u32)__builtin_bit_cast(u16, ha) | ((u32)__builtin_bit_cast(u16, hb) << 16);
#endif
}
// load weight elems {i,i+1} (i even), scale by s, pack to f16x2
template<bool BFM>
__device__ __forceinline__ u32 ldpacks(const void* p, int i, float s) {
  float a, b;
  if (BFM) {
    u32 pr = *(const u32*)((const u16*)p + i);
    a = __uint_as_float(pr << 16);
    b = __uint_as_float(pr & 0xffff0000u);
  } else {
    a = ((const float*)p)[i];
    b = ((const float*)p)[i + 1];
  }
  return packrtz(a * s, b * s);
}
__device__ __forceinline__ float exp2fast(float x) {
#if __has_builtin(__builtin_amdgcn_exp2f)
  return __builtin_amdgcn_exp2f(x);   // v_exp_f32 (exp2) directly
#else
  return __expf(x * 0.6931471805599453f);
#endif
}
// Gate pre-activations arrive PRE-SCALED: sig gates by -log2e, tanh gate by
// +2*log2e, so each nonlinearity is exp2 + add + rcp with no multiply.
__device__ __forceinline__ float combine(const float acc[4], float& c) {
  float ig = __builtin_amdgcn_rcpf(1.0f + exp2fast(acc[0]));
  float fg = __builtin_amdgcn_rcpf(1.0f + exp2fast(acc[1]));
  float gg = 1.0f - 2.0f * __builtin_amdgcn_rcpf(1.0f + exp2fast(acc[2]));
  float og = __builtin_amdgcn_rcpf(1.0f + exp2fast(acc[3]));
  c = fg * c + ig * gg;
  float th = 1.0f - 2.0f * __builtin_amdgcn_rcpf(1.0f + exp2fast((2.0f * L2E) * c));
  return og * th;
}
// packed f16 dual-MAC into f32
__device__ __forceinline__ float dot2f(u32 w, u32 h, float acc) {
#if __has_builtin(__builtin_amdgcn_fdot2)
  return __builtin_amdgcn_fdot2(__builtin_bit_cast(half2v, w),
                                __builtin_bit_cast(half2v, h), acc, false);
#else
  half2v a = __builtin_bit_cast(half2v, w), b = __builtin_bit_cast(half2v, h);
  acc = fmaf((float)a.x, (float)b.x, acc);
  return fmaf((float)a.y, (float)b.y, acc);
#endif
}
// sum of v across the lane<32 / lane>=32 halves, result in ALL lanes.
__device__ __forceinline__ float xhalfsum(float v) {
#if __has_builtin(__builtin_amdgcn_permlane32_swap)
  int2v r = __builtin_amdgcn_permlane32_swap(__float_as_int(v),
                                             __float_as_int(v), false, false);
  return __int_as_float(r.x) + __int_as_float(r.y);
#else
  return v + __shfl_xor(v, 32, 64);
#endif
}
// unpack two uint4 LDS slices into 8 packed-f16x2 dwords
__device__ __forceinline__ void ld8(const _Float16* p, u32 hh[8]) {
  const uint4* q = (const uint4*)p;
  uint4 a = q[0], b = q[1];
  hh[0] = a.x; hh[1] = a.y; hh[2] = a.z; hh[3] = a.w;
  hh[4] = b.x; hh[5] = b.y; hh[6] = b.z; hh[7] = b.w;
}

template<bool BFM>
__device__ __forceinline__ void run(
    const void* xg,
    const void* Wih_f0, const void* Whh_f0, const void* b_f0,
    const void* Wih_f1, const void* Whh_f1, const void* b_f1,
    const void* Wih_b0, const void* Whh_b0, const void* b_b0,
    const void* Wih_b1, const void* Whh_b1, const void* b_b1,
    const void* Wlin, const void* blin, const int* futp, void* outp,
    _Float16 (*h0b)[32], _Float16 (*hf1L)[32], float* pfs, int tid, int bid) {
  const int wv = tid >> 6;          // 0 = fwd pair, 1 = bwd pair
  const int lane = tid & 63;
  const int j = lane & 31;          // cell index
  const int h = lane >> 5;          // k-half: cols [16h, 16h+16)
  const int gb = bid;               // 1 batch per block

  const void* s0  = wv ? Whh_b0 : Whh_f0;
  const void* sA  = wv ? Wih_b1 : Wih_f1;
  const void* sB  = wv ? Whh_b1 : Whh_f1;
  const void* pb0 = wv ? b_b0 : b_f0;
  const void* pb1 = wv ? b_b1 : b_f1;
  const void* pwx = wv ? Wih_b0 : Wih_f0;

  // ---- per-lane weights: 96 dw packed f16x2 (k-split), gate-prescaled ----
  u32 w0[32];    // layer-0 rec: 4 gates x 8 dw (own k-half)
  u32 w1[64];    // layer-1: 4 gates x (8 inp + 8 rec) dw
  u32 wxb0[4];   // packed (Wih0*s, b0*s); zero in h=1 half
  float b1v[4];
#pragma unroll
  for (int g = 0; g < 4; ++g) {
    const float s = (g == 2) ? (2.0f * L2E) : (-L2E);
    const int r = (g * 32 + j) * 32 + 16 * h;
#pragma unroll
    for (int t = 0; t < 8; ++t) w0[g * 8 + t] = ldpacks<BFM>(s0, r + 2 * t, s);
#pragma unroll
    for (int t = 0; t < 8; ++t) w1[g * 16 + t] = ldpacks<BFM>(sA, r + 2 * t, s);
#pragma unroll
    for (int t = 0; t < 8; ++t) w1[g * 16 + 8 + t] = ldpacks<BFM>(sB, r + 2 * t, s);
    wxb0[g] = h ? 0u
                : packrtz(ldin<BFM>(pwx, g * 32 + j) * s,
                          ldin<BFM>(pb0, g * 32 + j) * s);
    b1v[g] = h ? 0.f : ldin<BFM>(pb1, g * 32 + j) * s;
  }
  const float wl  = h ? 0.f : ldin<BFM>(Wlin, wv * 32 + j);  // zero in h=1 half
  const float blv = ldin<BFM>(blin, 0);
  const int fut = *futp;

  // zero init LDS state: h0(-1)=0, hf1(-1)=0 (both parities), partials
  if (tid < 32) {
    h0b[0][tid] = (_Float16)0.f; h0b[1][tid] = (_Float16)0.f;
    hf1L[0][tid] = (_Float16)0.f; hf1L[1][tid] = (_Float16)0.f;
  }
  if (tid == 0) { pfs[0] = 0.f; pfs[1] = 0.f; }
  BARRIER();

  // fwd wave computes step t=u; bwd wave runs one step skewed (t' = u-1).
  float c0 = 0.f, c1 = 0.f;
  float x_cur = ldin<BFM>(xg, (wv ? ((fut + 1) & (SS - 1)) : 0) * BB + gb);

  for (int u = 0; u <= SS; ++u) {
    BARRIER();   // F's iter-(u-1) hf1/pf writes now visible

    // reads of prev-iter cross-wave data (buffer (u-1)&1 == (u+1)&1)
    u32 rr[8];
    ld8(&hf1L[(u + 1) & 1][16 * h], rr);     // hf1(u-1) slice, both waves
    float pfv = pfs[(u + 1) & 1];            // F partial(u-1) (+blv), used by B

    // own layer-0 h(u-1) slice
    u32 hh[8];
    ld8(&h0b[wv][16 * h], hh);

    // x prefetch for next iter
    int idxn = wv ? ((fut - u) & (SS - 1)) : ((u + 1 < SS) ? (u + 1) : (SS - 1));
    float x_n = ldin<BFM>(xg, idxn * BB + gb);

    // ---- layer 0 (F: f0@u ; B: b0@u-1), own k-half only ----
    float acc[4];
    u32 xp = packrtz(x_cur, 1.0f);
#pragma unroll
    for (int g = 0; g < 4; ++g) acc[g] = dot2f(wxb0[g], xp, 0.0f);
#pragma unroll
    for (int t = 0; t < 8; ++t) {
#pragma unroll
      for (int g = 0; g < 4; ++g) acc[g] = dot2f(w0[g * 8 + t], hh[t], acc[g]);
    }
#pragma unroll
    for (int g = 0; g < 4; ++g) acc[g] = xhalfsum(acc[g]);  // full K=32 sums
    float hn0 = combine(acc, c0);
    if ((u == 0) && wv) { hn0 = 0.f; c0 = 0.f; }  // bwd u=0 computed t'=-1 garbage
    h0b[wv][j] = (_Float16)hn0;   // both halves write same value (benign dup)
    CFENCE();                     // per-wave DS in-order covers the RAW

    // new layer-0 h slice (input to layer 1)
    u32 nn[8];
    ld8(&h0b[wv][16 * h], nn);

    // ---- layer 1 (F: f1@u ; B: b1@u-1, rec = hf1(u-1) per ref bug) ----
#pragma unroll
    for (int g = 0; g < 4; ++g) acc[g] = b1v[g];
#pragma unroll
    for (int t = 0; t < 8; ++t) {
#pragma unroll
      for (int g = 0; g < 4; ++g) acc[g] = dot2f(w1[g * 16 + t], nn[t], acc[g]);
    }
#pragma unroll
    for (int t = 0; t < 8; ++t) {
#pragma unroll
      for (int g = 0; g < 4; ++g)
        acc[g] = dot2f(w1[g * 16 + 8 + t], rr[t], acc[g]);
    }
#pragma unroll
    for (int g = 0; g < 4; ++g) acc[g] = xhalfsum(acc[g]);  // full K=64 sums
    float hn1 = combine(acc, c1);
    if ((u == 0) && wv) c1 = 0.f;

    // ---- per-wave output partial: sum of wl*hn1 over 64 lanes (wl=0 in h=1) ----
    float v = wl * hn1;
    DPPADD(v, 0x111, 0xf);  // row_shr:1
    DPPADD(v, 0x112, 0xf);  // row_shr:2
    DPPADD(v, 0x114, 0xf);  // row_shr:4
    DPPADD(v, 0x118, 0xf);  // row_shr:8
    DPPADD(v, 0x142, 0xa);  // row_bcast:15
    DPPADD(v, 0x143, 0xc);  // row_bcast:31 -> lane 63 = wave total

    if (!wv) {
      // F publishes hf1(u) + its output partial (blv folded in here, once)
      hf1L[u & 1][j] = (_Float16)hn1;       // dup write benign
      if (lane == 63) pfs[u & 1] = v + blv;
    } else if (u > 0 && lane == 63) {
      float o = v + pfv;                    // pf(u-1)+blv + pb(u-1)
      size_t pos = (size_t)gb * SS + (size_t)(u - 1);
      if (BFM) ((u16*)outp)[pos] = f2bf(o);
      else     ((float*)outp)[pos] = o;
    }
    x_cur = x_n;
  }
}

// 128 thr/block, min 4 waves/EU -> hard 128-VGPR cap; 2048 blocks = 8/CU,
// 16 waves/CU = 4 waves/SIMD, all co-resident.
__global__ void __launch_bounds__(NT, 4) lstm_kernel(
    const void* __restrict__ xg,
    const void* Wih_f0, const void* Whh_f0, const void* b_f0,
    const void* Wih_f1, const void* Whh_f1, const void* b_f1,
    const void* Wih_b0, const void* Whh_b0, const void* b_b0,
    const void* Wih_b1, const void* Whh_b1, const void* b_b1,
    const void* Wlin, const void* blin, const int* __restrict__ futp,
    void* __restrict__ outp) {
  __shared__ __align__(16) _Float16 h0s[2][32];    // layer-0 h per direction
  __shared__ __align__(16) _Float16 hf1s[2][32];   // hf1 double-buffer (cross-wave)
  __shared__ float pfss[2];                        // F output partial (+blv)

  // dtype detection (uniform): bf16-pairs read as fp32 are implausible as N(0,1)
  bool bfm;
  {
    const float* xf = (const float*)xg;
    int bad = 0;
    for (int i = 0; i < 64; ++i) {
      float a = fabsf(xf[i]);
      bool ok = (a == 0.0f) || (a > 1e-8f && a < 1e4f);
      if (!ok) bad = 1;
    }
    bfm = (bad != 0);
  }

  if (bfm)
    run<true>(xg, Wih_f0, Whh_f0, b_f0, Wih_f1, Whh_f1, b_f1,
              Wih_b0, Whh_b0, b_b0, Wih_b1, Whh_b1, b_b1,
              Wlin, blin, futp, outp, h0s, hf1s, pfss, threadIdx.x, blockIdx.x);
  else
    run<false>(xg, Wih_f0, Whh_f0, b_f0, Wih_f1, Whh_f1, b_f1,
               Wih_b0, Whh_b0, b_b0, Wih_b1, Whh_b1, b_b1,
               Wlin, blin, futp, outp, h0s, hf1s, pfss, threadIdx.x, blockIdx.x);
}

extern "C" void kernel_launch(void* const* d_in, const int* in_sizes, int n_in,
                              void* d_out, int out_size, void* d_ws, size_t ws_size,
                              hipStream_t stream) {
  (void)in_sizes; (void)n_in; (void)out_size; (void)d_ws; (void)ws_size;
  lstm_kernel<<<dim3(GRID), dim3(NT), 0, stream>>>(
      d_in[0], d_in[1], d_in[2], d_in[3], d_in[4], d_in[5], d_in[6],
      d_in[7], d_in[8], d_in[9], d_in[10], d_in[11], d_in[12],
      d_in[13], d_in[14], (const int*)d_in[15], d_out);
}

// Round 4
// 1229.462 us; speedup vs baseline: 1.7059x; 1.7059x over previous
//
#include <hip/hip_runtime.h>

#define SS 1024
#define BB 2048
#define NT 512     // 8 waves/block
#define GRID 256   // 8 batches/block -> full 2048; 1 block/CU on 256 CUs
#define G8 8

typedef unsigned int u32;
typedef unsigned short u16;
typedef _Float16 f16x4 __attribute__((ext_vector_type(4)));
typedef float f32x4 __attribute__((ext_vector_type(4)));
typedef u32 u32x2 __attribute__((ext_vector_type(2)));
typedef __fp16 fp16x2 __attribute__((ext_vector_type(2)));

#define L2E 1.4426950408889634f

// lgkmcnt drain + workgroup barrier (vmcnt NOT drained: x prefetch stays live)
#define BARRIER() asm volatile("s_waitcnt lgkmcnt(0)\n\ts_barrier" ::: "memory")

// DPP add of cross-lane shifted copy (VALU pipe)
#define DPPADD(v, ctrl, rm)                                                   \
  do {                                                                        \
    int _t = __builtin_amdgcn_update_dpp(0, __float_as_int(v), (ctrl), (rm),  \
                                         0xf, true);                          \
    (v) += __int_as_float(_t);                                                \
  } while (0)

// ---------- helpers ----------
__device__ __forceinline__ u16 f2bf(float f) {
  u32 u = __float_as_uint(f);
  return (u16)((u + 0x7fffu + ((u >> 16) & 1u)) >> 16);
}
template<bool BFM>
__device__ __forceinline__ float ldin(const void* p, int i) {
  if (BFM) { u16 v = ((const u16*)p)[i]; return __uint_as_float(((u32)v) << 16); }
  return ((const float*)p)[i];
}
__device__ __forceinline__ u32 packrtz(float lo, float hi) {
#if __has_builtin(__builtin_amdgcn_cvt_pkrtz)
  fp16x2 h = __builtin_amdgcn_cvt_pkrtz(lo, hi);
  return __builtin_bit_cast(u32, h);
#else
  _Float16 ha = (_Float16)lo, hb = (_Float16)hi;
  return (u32)__builtin_bit_cast(u16, ha) | ((u32)__builtin_bit_cast(u16, hb) << 16);
#endif
}
// load weight elems {i,i+1} (i even), scale, pack f16x2
template<bool BFM>
__device__ __forceinline__ u32 ldpacks(const void* p, int i, float s) {
  float a, b;
  if (BFM) {
    u32 pr = *(const u32*)((const u16*)p + i);
    a = __uint_as_float(pr << 16);
    b = __uint_as_float(pr & 0xffff0000u);
  } else {
    a = ((const float*)p)[i];
    b = ((const float*)p)[i + 1];
  }
  return packrtz(a * s, b * s);
}
__device__ __forceinline__ float exp2fast(float x) {
#if __has_builtin(__builtin_amdgcn_exp2f)
  return __builtin_amdgcn_exp2f(x);
#else
  return __expf(x * 0.6931471805599453f);
#endif
}
// pre-acts arrive PRE-SCALED: sigmoid gates by -log2e, tanh gate by +2log2e
__device__ __forceinline__ float combine(const float acc[4], float& c) {
  float ig = __builtin_amdgcn_rcpf(1.0f + exp2fast(acc[0]));
  float fg = __builtin_amdgcn_rcpf(1.0f + exp2fast(acc[1]));
  float gg = 1.0f - 2.0f * __builtin_amdgcn_rcpf(1.0f + exp2fast(acc[2]));
  float og = __builtin_amdgcn_rcpf(1.0f + exp2fast(acc[3]));
  c = fg * c + ig * gg;
  float th = 1.0f - 2.0f * __builtin_amdgcn_rcpf(1.0f + exp2fast((2.0f * L2E) * c));
  return og * th;
}
__device__ __forceinline__ f32x4 mfma16(f16x4 a, f16x4 b, f32x4 c) {
  return __builtin_amdgcn_mfma_f32_16x16x16f16(a, b, c, 0, 0, 0);
}
// B-frag from packed-[cellpair][bslot] LDS: dwords cp, cp+1 at column bcol
__device__ __forceinline__ f16x4 bfrag(const u32* base, int cp, int bcol) {
  u32x2 v;
  v.x = base[cp * 19 + bcol];
  v.y = base[(cp + 1) * 19 + bcol];
  return __builtin_bit_cast(f16x4, v);
}
__device__ __forceinline__ u16 f16bits(float x) {
  _Float16 h = (_Float16)x;
  return __builtin_bit_cast(u16, h);
}

// LDS geometry:
//  h0l / hf1l: [2][16 cellpairs][19 u32-slots]   (slot = batch col, 0..15 used)
//  prel:       [2 dir][8 batch][132 f32]  row = cell*4 + gate  (cell-major)
//  outp:       [8 wave][8 batch] f32 partials
template<bool BFM>
__device__ __forceinline__ void run(
    const void* xg,
    const void* Wih_f0, const void* Whh_f0, const void* b_f0,
    const void* Wih_f1, const void* Whh_f1, const void* b_f1,
    const void* Wih_b0, const void* Whh_b0, const void* b_b0,
    const void* Wih_b1, const void* Whh_b1, const void* b_b1,
    const void* Wlin, const void* blin, const int* futp, void* outp_g,
    u32 (*h0l)[16 * 19], u32 (*hf1l)[16 * 19], float (*prel)[8 * 132],
    float* outp, int tid, int bid) {
  const int wv = tid >> 6, lane = tid & 63;
  const int dirv = wv & 1;          // 0 = fwd pair, 1 = bwd pair
  const int wq = wv >> 1;           // gate index for MFMA duty (tiles 2wq,2wq+1)
  const int m = lane & 15, q = lane >> 4;            // MFMA lane coords
  const int cell = wq * 8 + (lane & 7), bb = lane >> 3;  // combine duty
  const int gb8 = bid * G8;

  const void* s0  = dirv ? Whh_b0 : Whh_f0;
  const void* sA  = dirv ? Wih_b1 : Wih_f1;
  const void* sB  = dirv ? Whh_b1 : Whh_f1;
  const void* pb0 = dirv ? b_b0 : b_f0;
  const void* pb1 = dirv ? b_b1 : b_f1;
  const void* pwx = dirv ? Wih_b0 : Wih_f0;

  // ---- MFMA A-fragments (weights), register-resident: 24 dw/lane ----
  // A layout (16x16x16 f16): lane holds A[m][4q + j], j=0..3, per k-step.
  f16x4 w0f[2][2];   // [tile t][kstep s]  layer-0 rec (K=32)
  f16x4 w1f[2][4];   // [tile t][kstep s]  layer-1 (K=64: s<2 inp, s>=2 rec)
  const float sgw = (wq == 2) ? (2.0f * L2E) : (-L2E);  // uniform: gate = wq
#pragma unroll
  for (int t = 0; t < 2; ++t) {
    const int rb = (16 * (2 * wq + t) + m) * 32;
#pragma unroll
    for (int s = 0; s < 2; ++s) {
      u32x2 v;
      v.x = ldpacks<BFM>(s0, rb + 16 * s + 4 * q + 0, sgw);
      v.y = ldpacks<BFM>(s0, rb + 16 * s + 4 * q + 2, sgw);
      w0f[t][s] = __builtin_bit_cast(f16x4, v);
    }
#pragma unroll
    for (int s = 0; s < 4; ++s) {
      const void* W = (s < 2) ? sA : sB;
      const int col = (s & 1) * 16 + 4 * q;
      u32x2 v;
      v.x = ldpacks<BFM>(W, rb + col + 0, sgw);
      v.y = ldpacks<BFM>(W, rb + col + 2, sgw);
      w1f[t][s] = __builtin_bit_cast(f16x4, v);
    }
  }
  // ---- combine-duty constants (per-cell) ----
  float wxv[4], b0v[4], b1v[4];
#pragma unroll
  for (int g = 0; g < 4; ++g) {
    const float sg = (g == 2) ? (2.0f * L2E) : (-L2E);
    wxv[g] = ldin<BFM>(pwx, g * 32 + cell) * sg;
    b0v[g] = ldin<BFM>(pb0, g * 32 + cell) * sg;
    b1v[g] = ldin<BFM>(pb1, g * 32 + cell) * sg;
  }
  const float wl  = ldin<BFM>(Wlin, dirv * 32 + cell);
  const float blv = ldin<BFM>(blin, 0);
  const int fut = *futp;

  // zero-init h/hf LDS (junk cols read by MFMA B-frags must be finite)
  for (int i = tid; i < 2 * 16 * 19; i += NT) {
    ((u32*)h0l)[i] = 0u;
    ((u32*)hf1l)[i] = 0u;
  }
  __syncthreads();

  float c0 = 0.f, c1 = 0.f, hf1_prev = 0.f;
  float x_cur = ldin<BFM>(xg, (dirv ? ((fut + 1) & (SS - 1)) : 0) * BB + gb8 + bb);

  for (int u = 0; u <= SS; ++u) {
    // x prefetch for iter u+1 (vmcnt not drained at barriers)
    const int nidx = dirv ? ((fut - u) & (SS - 1)) : ((u + 1 < SS) ? u + 1 : SS - 1);
    float x_nxt = ldin<BFM>(xg, nidx * BB + gb8 + bb);

    // ---- PH1: layer-0 MFMA (rec from h0(u-1)) ----
    {
      const u32* hb = h0l[dirv];
      f32x4 a0 = {0.f, 0.f, 0.f, 0.f}, a1 = {0.f, 0.f, 0.f, 0.f};
#pragma unroll
      for (int s = 0; s < 2; ++s) {
        f16x4 B = bfrag(hb, s * 8 + 2 * q, m);
        a0 = mfma16(w0f[0][s], B, a0);
        a1 = mfma16(w0f[1][s], B, a1);
      }
      if (m < 8) {  // real batch cols only
        float* pw = &prel[dirv][m * 132 + wq];
#pragma unroll
        for (int r = 0; r < 4; ++r) {
          pw[(4 * q + r) * 4]        = a0[r];
          pw[(16 + 4 * q + r) * 4]   = a1[r];
        }
      }
    }
    BARRIER();

    // ---- PH2: layer-0 combine (1 cell-instance per lane) ----
    {
      f32x4 p = *(const f32x4*)&prel[dirv][bb * 132 + cell * 4];
      float acc[4];
#pragma unroll
      for (int g = 0; g < 4; ++g) acc[g] = p[g] + fmaf(wxv[g], x_cur, b0v[g]);
      float hn0 = combine(acc, c0);
      if (u == 0 && dirv) { hn0 = 0.f; c0 = 0.f; }  // bwd t'=-1 garbage
      ((u16*)&h0l[dirv][(cell >> 1) * 19 + bb])[cell & 1] = f16bits(hn0);
    }
    BARRIER();

    // ---- PH3: layer-1 MFMA (inp = h0(u), rec = hf1(u-1) per ref bug) ----
    {
      const u32* hb  = h0l[dirv];
      const u32* hfb = hf1l[(u + 1) & 1];
      f32x4 d0 = {0.f, 0.f, 0.f, 0.f}, d1 = {0.f, 0.f, 0.f, 0.f};
#pragma unroll
      for (int s = 0; s < 2; ++s) {
        f16x4 B = bfrag(hb, s * 8 + 2 * q, m);
        d0 = mfma16(w1f[0][s], B, d0);
        d1 = mfma16(w1f[1][s], B, d1);
      }
#pragma unroll
      for (int s = 0; s < 2; ++s) {
        f16x4 B = bfrag(hfb, s * 8 + 2 * q, m);
        d0 = mfma16(w1f[0][2 + s], B, d0);
        d1 = mfma16(w1f[1][2 + s], B, d1);
      }
      if (m < 8) {
        float* pw = &prel[dirv][m * 132 + wq];
#pragma unroll
        for (int r = 0; r < 4; ++r) {
          pw[(4 * q + r) * 4]      = d0[r];
          pw[(16 + 4 * q + r) * 4] = d1[r];
        }
      }
    }
    BARRIER();

    // ---- PH4: layer-1 combine + head partials ----
    {
      f32x4 p = *(const f32x4*)&prel[dirv][bb * 132 + cell * 4];
      float acc[4];
#pragma unroll
      for (int g = 0; g < 4; ++g) acc[g] = p[g] + b1v[g];
      float hn1 = combine(acc, c1);
      if (u == 0 && dirv) c1 = 0.f;
      if (!dirv)  // publish hf1(u), parity u&1 (read next iter + by bwd bug-share)
        ((u16*)&hf1l[u & 1][(cell >> 1) * 19 + bb])[cell & 1] = f16bits(hn1);
      float myh = dirv ? hn1 : hf1_prev;  // head needs hf1(u-1), hb1(u-1)
      hf1_prev = hn1;
      float v = wl * myh;
      DPPADD(v, 0x111, 0xf);  // row_shr:1
      DPPADD(v, 0x112, 0xf);  // row_shr:2
      DPPADD(v, 0x114, 0xf);  // row_shr:4 -> lane 8b+7 = sum of 8 cells
      if ((lane & 7) == 7) outp[wv * 8 + bb] = v;
    }
    BARRIER();

    // ---- PH5: head finalize, wave 0 only, out[s=u-1] ----
    if (wv == 0 && u > 0) {
      float pr = outp[(lane & 7) * 8 + (lane >> 3)];  // [wv=lane&7][b=lane>>3]
      DPPADD(pr, 0x111, 0xf);
      DPPADD(pr, 0x112, 0xf);
      DPPADD(pr, 0x114, 0xf);
      if ((lane & 7) == 7) {
        float o = pr + blv;
        size_t pos = (size_t)(gb8 + (lane >> 3)) * SS + (size_t)(u - 1);
        if (BFM) ((u16*)outp_g)[pos] = f2bf(o);
        else     ((float*)outp_g)[pos] = o;
      }
    }
    x_cur = x_nxt;
  }
}

__global__ void __launch_bounds__(NT, 2) lstm_kernel(
    const void* __restrict__ xg,
    const void* Wih_f0, const void* Whh_f0, const void* b_f0,
    const void* Wih_f1, const void* Whh_f1, const void* b_f1,
    const void* Wih_b0, const void* Whh_b0, const void* b_b0,
    const void* Wih_b1, const void* Whh_b1, const void* b_b1,
    const void* Wlin, const void* blin, const int* __restrict__ futp,
    void* __restrict__ outp) {
  __shared__ u32 h0s[2][16 * 19];
  __shared__ u32 hf1s[2][16 * 19];
  __shared__ __align__(16) float pres[2][8 * 132];
  __shared__ float outps[64];

  // dtype detection (uniform): bf16-pairs read as fp32 implausible as N(0,1)
  bool bfm;
  {
    const float* xf = (const float*)xg;
    int bad = 0;
    for (int i = 0; i < 64; ++i) {
      float a = fabsf(xf[i]);
      bool ok = (a == 0.0f) || (a > 1e-8f && a < 1e4f);
      if (!ok) bad = 1;
    }
    bfm = (bad != 0);
  }

  if (bfm)
    run<true>(xg, Wih_f0, Whh_f0, b_f0, Wih_f1, Whh_f1, b_f1,
              Wih_b0, Whh_b0, b_b0, Wih_b1, Whh_b1, b_b1,
              Wlin, blin, futp, outp, h0s, hf1s, pres, outps,
              threadIdx.x, blockIdx.x);
  else
    run<false>(xg, Wih_f0, Whh_f0, b_f0, Wih_f1, Whh_f1, b_f1,
               Wih_b0, Whh_b0, b_b0, Wih_b1, Whh_b1, b_b1,
               Wlin, blin, futp, outp, h0s, hf1s, pres, outps,
               threadIdx.x, blockIdx.x);
}

extern "C" void kernel_launch(void* const* d_in, const int* in_sizes, int n_in,
                              void* d_out, int out_size, void* d_ws, size_t ws_size,
                              hipStream_t stream) {
  (void)in_sizes; (void)n_in; (void)out_size; (void)d_ws; (void)ws_size;
  lstm_kernel<<<dim3(GRID), dim3(NT), 0, stream>>>(
      d_in[0], d_in[1], d_in[2], d_in[3], d_in[4], d_in[5], d_in[6],
      d_in[7], d_in[8], d_in[9], d_in[10], d_in[11], d_in[12],
      d_in[13], d_in[14], (const int*)d_in[15], d_out);
}

// Round 5
// 1161.606 us; speedup vs baseline: 1.8056x; 1.0584x over previous
//
#include <hip/hip_runtime.h>

#define SS 1024
#define BB 2048
#define NT 512     // 8 waves: wv = dir + 2*wq  (dir = wv&1, wq = wv>>1)
#define GRID 256   // 8 batches/block, full 2048; 1 block/CU
#define G8 8

typedef unsigned int u32;
typedef unsigned short u16;
typedef _Float16 f16x4 __attribute__((ext_vector_type(4)));
typedef float f32x4 __attribute__((ext_vector_type(4)));
typedef u32 u32x2 __attribute__((ext_vector_type(2)));
typedef __fp16 fp16x2 __attribute__((ext_vector_type(2)));

#define L2E 1.4426950408889634f

// lgkmcnt drain + barrier (vmcnt NOT drained: x prefetch stays in flight)
#define BARRIER() asm volatile("s_waitcnt lgkmcnt(0)\n\ts_barrier" ::: "memory")

// ---------- helpers ----------
__device__ __forceinline__ u16 f2bf(float f) {
  u32 u = __float_as_uint(f);
  return (u16)((u + 0x7fffu + ((u >> 16) & 1u)) >> 16);
}
template<bool BFM>
__device__ __forceinline__ float ldin(const void* p, int i) {
  if (BFM) { u16 v = ((const u16*)p)[i]; return __uint_as_float(((u32)v) << 16); }
  return ((const float*)p)[i];
}
__device__ __forceinline__ u32 packrtz(float lo, float hi) {
#if __has_builtin(__builtin_amdgcn_cvt_pkrtz)
  fp16x2 h = __builtin_amdgcn_cvt_pkrtz(lo, hi);
  return __builtin_bit_cast(u32, h);
#else
  _Float16 ha = (_Float16)lo, hb = (_Float16)hi;
  return (u32)__builtin_bit_cast(u16, ha) | ((u32)__builtin_bit_cast(u16, hb) << 16);
#endif
}
// load weight elems {i,i+1} (i even), scale, pack f16x2
template<bool BFM>
__device__ __forceinline__ u32 ldpacks(const void* p, int i, float s) {
  float a, b;
  if (BFM) {
    u32 pr = *(const u32*)((const u16*)p + i);
    a = __uint_as_float(pr << 16);
    b = __uint_as_float(pr & 0xffff0000u);
  } else {
    a = ((const float*)p)[i];
    b = ((const float*)p)[i + 1];
  }
  return packrtz(a * s, b * s);
}
__device__ __forceinline__ float exp2fast(float x) {
#if __has_builtin(__builtin_amdgcn_exp2f)
  return __builtin_amdgcn_exp2f(x);
#else
  return __expf(x * 0.6931471805599453f);
#endif
}
// pre-acts arrive PRE-SCALED: sigmoid gates by -log2e, tanh gate by +2log2e
__device__ __forceinline__ float combine(const float acc[4], float& c) {
  float ig = __builtin_amdgcn_rcpf(1.0f + exp2fast(acc[0]));
  float fg = __builtin_amdgcn_rcpf(1.0f + exp2fast(acc[1]));
  float gg = 1.0f - 2.0f * __builtin_amdgcn_rcpf(1.0f + exp2fast(acc[2]));
  float og = __builtin_amdgcn_rcpf(1.0f + exp2fast(acc[3]));
  c = fg * c + ig * gg;
  float th = 1.0f - 2.0f * __builtin_amdgcn_rcpf(1.0f + exp2fast((2.0f * L2E) * c));
  return og * th;
}
__device__ __forceinline__ f32x4 mfma16(f16x4 a, f16x4 b, f32x4 c) {
  return __builtin_amdgcn_mfma_f32_16x16x16f16(a, b, c, 0, 0, 0);
}
__device__ __forceinline__ u16 f16bits(float x) {
  _Float16 h = (_Float16)x;
  return __builtin_bit_cast(u16, h);
}

// LDS geometry (all batch-major, row stride 18 dwords = 72 B -> <=2-way banks):
//  h0l : [dir][par][16 batch][18 dw]  (f16 h0, cells 0..31 in first 16 dw)
//  hf1l: [par][16 batch][18 dw]
//  po  : [8 wave][8 batch] f32 head partials
template<bool BFM>
__device__ __forceinline__ void run(
    const void* xg,
    const void* Wih_f0, const void* Whh_f0, const void* b_f0,
    const void* Wih_f1, const void* Whh_f1, const void* b_f1,
    const void* Wih_b0, const void* Whh_b0, const void* b_b0,
    const void* Wih_b1, const void* Whh_b1, const void* b_b1,
    const void* Wlin, const void* blin, const int* futp, void* outp_g,
    u32* h0l, u32* hf1l, float* po, int tid, int bid) {
  const int wv = tid >> 6, lane = tid & 63;
  const int dirv = wv & 1, wq = wv >> 1;
  const int m = lane & 15, q = lane >> 4;
  const int gb8 = bid * G8;
  const int xb = gb8 + (m & 7);      // m>=8: duplicate batch (junk lanes, safe addr)

  const void* s0  = dirv ? Whh_b0 : Whh_f0;
  const void* sA  = dirv ? Wih_b1 : Wih_f1;
  const void* sB  = dirv ? Whh_b1 : Whh_f1;
  const void* pb0 = dirv ? b_b0 : b_f0;
  const void* pb1 = dirv ? b_b1 : b_f1;
  const void* pwx = dirv ? Wih_b0 : Wih_f0;

  // ---- A-fragments with CELL-MAJOR row permutation: W~[cell*4+gate] = W[gate*32+cell]
  // Lane (m,q), tile 2wq+t holds W~ row 16*tile+m  ->  gate = m&3, cell = 4*tile + (m>>2).
  // Then D rows 4q+r of tile = cell 4*tile+q, gate r: lane owns a full gate-quad.
  f16x4 w0f[2][2], w1i[2][2], w1r[2][2];
  const int gA = m & 3;
  const float sw = (gA == 2) ? (2.0f * L2E) : (-L2E);
#pragma unroll
  for (int t = 0; t < 2; ++t) {
    const int R = gA * 32 + 4 * (2 * wq + t) + (m >> 2);   // original row
#pragma unroll
    for (int s = 0; s < 2; ++s) {
      const int i0 = R * 32 + 16 * s + 4 * q;
      u32x2 v;
      v.x = ldpacks<BFM>(s0, i0, sw); v.y = ldpacks<BFM>(s0, i0 + 2, sw);
      w0f[t][s] = __builtin_bit_cast(f16x4, v);
      v.x = ldpacks<BFM>(sA, i0, sw); v.y = ldpacks<BFM>(sA, i0 + 2, sw);
      w1i[t][s] = __builtin_bit_cast(f16x4, v);
      v.x = ldpacks<BFM>(sB, i0, sw); v.y = ldpacks<BFM>(sB, i0 + 2, sw);
      w1r[t][s] = __builtin_bit_cast(f16x4, v);
    }
  }
  // ---- per-lane combine constants: cells cA = 8wq+q (tile 2wq), cB = cA+4 (tile 2wq+1)
  const int cA = 8 * wq + q, cB = cA + 4;
  float wxA[4], wxB[4], b0A[4], b0B[4], b1A[4], b1B[4];
#pragma unroll
  for (int r = 0; r < 4; ++r) {
    const float sg = (r == 2) ? (2.0f * L2E) : (-L2E);
    wxA[r] = ldin<BFM>(pwx, r * 32 + cA) * sg;
    wxB[r] = ldin<BFM>(pwx, r * 32 + cB) * sg;
    b0A[r] = ldin<BFM>(pb0, r * 32 + cA) * sg;
    b0B[r] = ldin<BFM>(pb0, r * 32 + cB) * sg;
    b1A[r] = ldin<BFM>(pb1, r * 32 + cA) * sg;
    b1B[r] = ldin<BFM>(pb1, r * 32 + cB) * sg;
  }
  const float wlA = ldin<BFM>(Wlin, dirv * 32 + cA);
  const float wlB = ldin<BFM>(Wlin, dirv * 32 + cB);
  const float blv = ldin<BFM>(blin, 0);
  const int fut = *futp;

  // zero LDS (rows m>=8 must stay zero: junk MFMA cols read them)
  for (int i = tid; i < 2 * 2 * 16 * 18; i += NT) h0l[i] = 0u;
  for (int i = tid; i < 2 * 16 * 18; i += NT) hf1l[i] = 0u;
  if (tid < 64) po[tid] = 0.f;
  __syncthreads();

  float c0A = 0.f, c0B = 0.f, c1A = 0.f, c1B = 0.f, prA = 0.f, prB = 0.f;
  float x_cur = ldin<BFM>(xg, (dirv ? ((fut + 1) & (SS - 1)) : 0) * BB + xb);

  for (int u = 0; u <= SS; ++u) {
    const int nidx = dirv ? ((fut - u) & (SS - 1)) : ((u + 1 < SS) ? u + 1 : SS - 1);
    const float x_nxt = ldin<BFM>(xg, nidx * BB + xb);   // stays in flight (no vmcnt drain)

    // ---- layer-0 MFMA: rec = h0(u-1), parity (u+1)&1 ----
    const u32x2* hb =
        (const u32x2*)&h0l[((dirv * 2 + ((u + 1) & 1)) * 16 + m) * 18];
    f32x4 a0 = {0.f, 0.f, 0.f, 0.f}, a1 = {0.f, 0.f, 0.f, 0.f};
#pragma unroll
    for (int s = 0; s < 2; ++s) {
      f16x4 B = __builtin_bit_cast(f16x4, hb[4 * s + q]);   // cells 16s+4q..+3, batch m
      a0 = mfma16(w0f[0][s], B, a0);
      a1 = mfma16(w0f[1][s], B, a1);
    }
    // ---- layer-0 combine, fully in-register (gate-quad per lane) ----
    float accA[4], accB[4];
#pragma unroll
    for (int r = 0; r < 4; ++r) {
      accA[r] = a0[r] + fmaf(wxA[r], x_cur, b0A[r]);
      accB[r] = a1[r] + fmaf(wxB[r], x_cur, b0B[r]);
    }
    float hnA = combine(accA, c0A);
    float hnB = combine(accB, c0B);
    if (u == 0 && dirv) { hnA = 0.f; hnB = 0.f; c0A = 0.f; c0B = 0.f; }  // bwd t'=-1
    if (m < 8) {
      u16* hw = (u16*)&h0l[((dirv * 2 + (u & 1)) * 16 + m) * 18];
      hw[cA] = f16bits(hnA);
      hw[cB] = f16bits(hnB);
    }
    BARRIER();   // B1: h0(u) visible

    // ---- layer-1 MFMA: inp = h0(u) [own dir], rec = hf1(u-1) [shared, ref bug] ----
    const u32x2* hi =
        (const u32x2*)&h0l[((dirv * 2 + (u & 1)) * 16 + m) * 18];
    const u32x2* hr = (const u32x2*)&hf1l[(((u + 1) & 1) * 16 + m) * 18];
    f32x4 d0 = {0.f, 0.f, 0.f, 0.f}, d1 = {0.f, 0.f, 0.f, 0.f};
#pragma unroll
    for (int s = 0; s < 2; ++s) {
      f16x4 B = __builtin_bit_cast(f16x4, hi[4 * s + q]);
      d0 = mfma16(w1i[0][s], B, d0);
      d1 = mfma16(w1i[1][s], B, d1);
    }
#pragma unroll
    for (int s = 0; s < 2; ++s) {
      f16x4 B = __builtin_bit_cast(f16x4, hr[4 * s + q]);
      d0 = mfma16(w1r[0][s], B, d0);
      d1 = mfma16(w1r[1][s], B, d1);
    }
    // ---- layer-1 combine ----
#pragma unroll
    for (int r = 0; r < 4; ++r) { accA[r] = d0[r] + b1A[r]; accB[r] = d1[r] + b1B[r]; }
    float h1A = combine(accA, c1A);
    float h1B = combine(accB, c1B);
    if (u == 0 && dirv) { c1A = 0.f; c1B = 0.f; }
    if (!dirv && m < 8) {   // fwd publishes hf1(u), parity u&1
      u16* hw = (u16*)&hf1l[((u & 1) * 16 + m) * 18];
      hw[cA] = f16bits(h1A);
      hw[cB] = f16bits(h1B);
    }
    // ---- head partial for t = u-1: fwd uses hf1(u-1) (prev), bwd uses hb1(u-1) (cur)
    float v = dirv ? fmaf(wlA, h1A, wlB * h1B) : fmaf(wlA, prA, wlB * prB);
    prA = h1A; prB = h1B;
    v += __shfl_xor(v, 16, 64);   // reduce over q
    v += __shfl_xor(v, 32, 64);
    if (lane < 8) po[wv * 8 + lane] = v;   // [wave][batch]
    BARRIER();   // B2: hf1(u) + po visible

    // ---- head finalize on wave 0 (reads po after B2; pre-B1(u+1), race-free) ----
    if (wv == 0 && u > 0) {
      float pr = po[lane];                 // [w = lane>>3][b = lane&7]
      pr += __shfl_xor(pr, 8, 64);
      pr += __shfl_xor(pr, 16, 64);
      pr += __shfl_xor(pr, 32, 64);
      if (lane < 8) {
        float o = pr + blv;
        size_t pos = (size_t)(gb8 + lane) * SS + (size_t)(u - 1);
        if (BFM) ((u16*)outp_g)[pos] = f2bf(o);
        else     ((float*)outp_g)[pos] = o;
      }
    }
    x_cur = x_nxt;
  }
}

__global__ void __launch_bounds__(NT, 2) lstm_kernel(
    const void* __restrict__ xg,
    const void* Wih_f0, const void* Whh_f0, const void* b_f0,
    const void* Wih_f1, const void* Whh_f1, const void* b_f1,
    const void* Wih_b0, const void* Whh_b0, const void* b_b0,
    const void* Wih_b1, const void* Whh_b1, const void* b_b1,
    const void* Wlin, const void* blin, const int* __restrict__ futp,
    void* __restrict__ outp) {
  __shared__ __align__(16) u32 h0s[2 * 2 * 16 * 18];
  __shared__ __align__(16) u32 hf1s[2 * 16 * 18];
  __shared__ __align__(16) float pos_[64];

  // dtype detection (uniform): bf16-pairs read as fp32 implausible as N(0,1)
  bool bfm;
  {
    const float* xf = (const float*)xg;
    int bad = 0;
    for (int i = 0; i < 64; ++i) {
      float a = fabsf(xf[i]);
      bool ok = (a == 0.0f) || (a > 1e-8f && a < 1e4f);
      if (!ok) bad = 1;
    }
    bfm = (bad != 0);
  }

  if (bfm)
    run<true>(xg, Wih_f0, Whh_f0, b_f0, Wih_f1, Whh_f1, b_f1,
              Wih_b0, Whh_b0, b_b0, Wih_b1, Whh_b1, b_b1,
              Wlin, blin, futp, outp, h0s, hf1s, pos_,
              threadIdx.x, blockIdx.x);
  else
    run<false>(xg, Wih_f0, Whh_f0, b_f0, Wih_f1, Whh_f1, b_f1,
               Wih_b0, Whh_b0, b_b0, Wih_b1, Whh_b1, b_b1,
               Wlin, blin, futp, outp, h0s, hf1s, pos_,
               threadIdx.x, blockIdx.x);
}

extern "C" void kernel_launch(void* const* d_in, const int* in_sizes, int n_in,
                              void* d_out, int out_size, void* d_ws, size_t ws_size,
                              hipStream_t stream) {
  (void)in_sizes; (void)n_in; (void)out_size; (void)d_ws; (void)ws_size;
  lstm_kernel<<<dim3(GRID), dim3(NT), 0, stream>>>(
      d_in[0], d_in[1], d_in[2], d_in[3], d_in[4], d_in[5], d_in[6],
      d_in[7], d_in[8], d_in[9], d_in[10], d_in[11], d_in[12],
      d_in[13], d_in[14], (const int*)d_in[15], d_out);
}

// Round 7
// 835.274 us; speedup vs baseline: 2.5110x; 1.3907x over previous
//
#include <hip/hip_runtime.h>

#define SS 1024
#define BB 2048
#define NT 512     // 8 waves: wv = dir + 2*wq  (dir = wv&1, wq = wv>>1)
#define GRID 256   // 8 batches/block, full 2048; 1 block/CU
#define G8 8

typedef unsigned int u32;
typedef unsigned short u16;
typedef _Float16 f16x4 __attribute__((ext_vector_type(4)));
typedef float f32x4 __attribute__((ext_vector_type(4)));
typedef u32 u32x2 __attribute__((ext_vector_type(2)));
typedef __fp16 fp16x2 __attribute__((ext_vector_type(2)));

#define L2E 1.4426950408889634f

// lgkmcnt drain + barrier (vmcnt NOT drained: x prefetch stays in flight)
#define BARRIER() asm volatile("s_waitcnt lgkmcnt(0)\n\ts_barrier" ::: "memory")

// ---------- helpers ----------
__device__ __forceinline__ u16 f2bf(float f) {
  u32 u = __float_as_uint(f);
  return (u16)((u + 0x7fffu + ((u >> 16) & 1u)) >> 16);
}
template<bool BFM>
__device__ __forceinline__ float ldin(const void* p, int i) {
  if (BFM) { u16 v = ((const u16*)p)[i]; return __uint_as_float(((u32)v) << 16); }
  return ((const float*)p)[i];
}
__device__ __forceinline__ u32 packrtz(float lo, float hi) {
#if __has_builtin(__builtin_amdgcn_cvt_pkrtz)
  fp16x2 h = __builtin_amdgcn_cvt_pkrtz(lo, hi);
  return __builtin_bit_cast(u32, h);
#else
  _Float16 ha = (_Float16)lo, hb = (_Float16)hi;
  return (u32)__builtin_bit_cast(u16, ha) | ((u32)__builtin_bit_cast(u16, hb) << 16);
#endif
}
template<bool BFM>
__device__ __forceinline__ u32 ldpacks(const void* p, int i, float s) {
  float a, b;
  if (BFM) {
    u32 pr = *(const u32*)((const u16*)p + i);
    a = __uint_as_float(pr << 16);
    b = __uint_as_float(pr & 0xffff0000u);
  } else {
    a = ((const float*)p)[i];
    b = ((const float*)p)[i + 1];
  }
  return packrtz(a * s, b * s);
}
__device__ __forceinline__ float exp2fast(float x) {
#if __has_builtin(__builtin_amdgcn_exp2f)
  return __builtin_amdgcn_exp2f(x);
#else
  return __expf(x * 0.6931471805599453f);
#endif
}
// pre-acts PRE-SCALED: sigmoid gates by -log2e, tanh gate by +2log2e
__device__ __forceinline__ float combine(const float acc[4], float& c) {
  float ig = __builtin_amdgcn_rcpf(1.0f + exp2fast(acc[0]));
  float fg = __builtin_amdgcn_rcpf(1.0f + exp2fast(acc[1]));
  float gg = 1.0f - 2.0f * __builtin_amdgcn_rcpf(1.0f + exp2fast(acc[2]));
  float og = __builtin_amdgcn_rcpf(1.0f + exp2fast(acc[3]));
  c = fg * c + ig * gg;
  float th = 1.0f - 2.0f * __builtin_amdgcn_rcpf(1.0f + exp2fast((2.0f * L2E) * c));
  return og * th;
}
__device__ __forceinline__ f32x4 mfma16(f16x4 a, f16x4 b, f32x4 c) {
  return __builtin_amdgcn_mfma_f32_16x16x16f16(a, b, c, 0, 0, 0);
}
__device__ __forceinline__ u16 f16bits(float x) {
  _Float16 h = (_Float16)x;
  return __builtin_bit_cast(u16, h);
}
// lane i <- lane i^8 within 16-lane rows (row_ror:8): half-swap
__device__ __forceinline__ float dppswap8(float v) {
  int t = __builtin_amdgcn_update_dpp(0, __float_as_int(v), 0x128, 0xf, 0xf, true);
  return __int_as_float(t);
}

// LDS (batch-major, row stride 18 dw -> conflict-free):
//  h0l : [dir][par][16 rows][18 dw]   rows 8..15 stay zero (junk MFMA cols)
//  hf1l: [par][16 rows][18 dw]
//  po  : [par][8 wave][8 batch] f32 head partials
//
// Schedule (ONE barrier/iter): at iter u —
//   L0 computes t=u (fwd) / t=u-1 (bwd); reads h0[par r=(u+1)&1], writes par w=u&1
//   L1 computes t=u-1 (fwd) / t=u-2 (bwd); inp = SAME h0[par r] frags as L0-rec,
//      rec = hf1[par r]; fwd writes hf1[par w]
//   head partials for t=u-2 -> po[par w]; finalize (wave 0) emits t=u-3 from po[par r]
template<bool BFM>
__device__ __forceinline__ void run(
    const void* xg,
    const void* Wih_f0, const void* Whh_f0, const void* b_f0,
    const void* Wih_f1, const void* Whh_f1, const void* b_f1,
    const void* Wih_b0, const void* Whh_b0, const void* b_b0,
    const void* Wih_b1, const void* Whh_b1, const void* b_b1,
    const void* Wlin, const void* blin, const int* futp, void* outp_g,
    u32* h0l, u32* hf1l, float* po, int tid, int bid) {
  const int wv = tid >> 6, lane = tid & 63;
  const int dirv = wv & 1, wq = wv >> 1;
  const int m = lane & 15, q = lane >> 4;
  const int half = m >> 3, bM = m & 7;
  const int gb8 = bid * G8;
  const int xb = gb8 + bM;

  const void* s0  = dirv ? Whh_b0 : Whh_f0;
  const void* sA  = dirv ? Wih_b1 : Wih_f1;
  const void* sB  = dirv ? Whh_b1 : Whh_f1;
  const void* pb0 = dirv ? b_b0 : b_f0;
  const void* pb1 = dirv ? b_b1 : b_f1;
  const void* pwx = dirv ? Wih_b0 : Wih_f0;

  // ---- A-fragments, CELL-MAJOR row permutation (identical to passing R5) ----
  f16x4 w0f[2][2], w1i[2][2], w1r[2][2];
  const int gA = m & 3;
  const float sw = (gA == 2) ? (2.0f * L2E) : (-L2E);
#pragma unroll
  for (int t = 0; t < 2; ++t) {
    const int R = gA * 32 + 4 * (2 * wq + t) + (m >> 2);
#pragma unroll
    for (int s = 0; s < 2; ++s) {
      const int i0 = R * 32 + 16 * s + 4 * q;
      u32x2 v;
      v.x = ldpacks<BFM>(s0, i0, sw); v.y = ldpacks<BFM>(s0, i0 + 2, sw);
      w0f[t][s] = __builtin_bit_cast(f16x4, v);
      v.x = ldpacks<BFM>(sA, i0, sw); v.y = ldpacks<BFM>(sA, i0 + 2, sw);
      w1i[t][s] = __builtin_bit_cast(f16x4, v);
      v.x = ldpacks<BFM>(sB, i0, sw); v.y = ldpacks<BFM>(sB, i0 + 2, sw);
      w1r[t][s] = __builtin_bit_cast(f16x4, v);
    }
  }
  // ---- per-lane combine constants: ONE cell per lane (junk-lane elimination) ----
  const int cA = 8 * wq + q, cB = cA + 4;
  const int cM = half ? cB : cA;
  float wxv[4], b0v[4], b1v[4];
#pragma unroll
  for (int r = 0; r < 4; ++r) {
    const float sg = (r == 2) ? (2.0f * L2E) : (-L2E);
    wxv[r] = ldin<BFM>(pwx, r * 32 + cM) * sg;
    b0v[r] = ldin<BFM>(pb0, r * 32 + cM) * sg;
    b1v[r] = ldin<BFM>(pb1, r * 32 + cM) * sg;
  }
  const float wlM = ldin<BFM>(Wlin, dirv * 32 + cM);
  const float blv = ldin<BFM>(blin, 0);
  const int fut = *futp;

  // zero LDS
  for (int i = tid; i < 2 * 2 * 16 * 18; i += NT) h0l[i] = 0u;
  for (int i = tid; i < 2 * 16 * 18; i += NT) hf1l[i] = 0u;
  if (tid < 128) po[tid] = 0.f;
  __syncthreads();

  float c0 = 0.f, c1 = 0.f, pr = 0.f;
  float x_cur = ldin<BFM>(xg, (dirv ? ((fut + 1) & (SS - 1)) : 0) * BB + xb);

  for (int u = 0; u <= SS + 2; ++u) {
    const int par_w = u & 1, par_r = (u + 1) & 1;
    const int nidx = dirv ? ((fut - u) & (SS - 1)) : ((u + 1 < SS) ? u + 1 : SS - 1);
    const float x_nxt = ldin<BFM>(xg, nidx * BB + xb);  // in flight across barrier

    // ---- shared B-frag reads: h0(prev) feeds BOTH L0-rec and L1-inp ----
    const u32x2* hbp = (const u32x2*)&h0l[((dirv * 2 + par_r) * 16 + m) * 18];
    const u32x2* hrp = (const u32x2*)&hf1l[(par_r * 16 + m) * 18];
    f16x4 Bs[2], Br[2];
#pragma unroll
    for (int s = 0; s < 2; ++s) {
      Bs[s] = __builtin_bit_cast(f16x4, hbp[4 * s + q]);
      Br[s] = __builtin_bit_cast(f16x4, hrp[4 * s + q]);
    }

    // ---- all 12 MFMAs of the phase (independent chains) ----
    f32x4 a0 = {0.f, 0.f, 0.f, 0.f}, a1 = {0.f, 0.f, 0.f, 0.f};
    f32x4 d0 = {0.f, 0.f, 0.f, 0.f}, d1 = {0.f, 0.f, 0.f, 0.f};
#pragma unroll
    for (int s = 0; s < 2; ++s) {
      a0 = mfma16(w0f[0][s], Bs[s], a0);
      a1 = mfma16(w0f[1][s], Bs[s], a1);
      d0 = mfma16(w1i[0][s], Bs[s], d0);
      d1 = mfma16(w1i[1][s], Bs[s], d1);
    }
#pragma unroll
    for (int s = 0; s < 2; ++s) {
      d0 = mfma16(w1r[0][s], Br[s], d0);
      d1 = mfma16(w1r[1][s], Br[s], d1);
    }

    // ---- head finalize (wave 0): emit out(u-3) from po[par r] ----
    if (wv == 0 && u >= 3) {
      float pz = po[par_r * 64 + lane];   // [w=lane>>3][b=lane&7]
      pz += __shfl_xor(pz, 8, 64);
      pz += __shfl_xor(pz, 16, 64);
      pz += __shfl_xor(pz, 32, 64);
      if (lane < 8) {
        float o = pz + blv;
        size_t pos = (size_t)(gb8 + lane) * SS + (size_t)(u - 3);
        if (BFM) ((u16*)outp_g)[pos] = f2bf(o);
        else     ((float*)outp_g)[pos] = o;
      }
    }

    // ---- L0 combine: one cell per lane (swap tile-B quads to upper half) ----
    float acc[4];
#pragma unroll
    for (int r = 0; r < 4; ++r) {
      float swp = dppswap8(a1[r]);
      acc[r] = (half ? swp : a0[r]) + fmaf(wxv[r], x_cur, b0v[r]);
    }
    float hn0 = combine(acc, c0);
    if (u == 0 && dirv) { hn0 = 0.f; c0 = 0.f; }   // bwd t'=-1 garbage
    ((u16*)&h0l[((dirv * 2 + par_w) * 16 + bM) * 18])[cM] = f16bits(hn0);

    // ---- L1 combine ----
#pragma unroll
    for (int r = 0; r < 4; ++r) {
      float swp = dppswap8(d1[r]);
      acc[r] = (half ? swp : d0[r]) + b1v[r];
    }
    float hn1 = combine(acc, c1);
    if (dirv) { if (u <= 1) c1 = 0.f; }            // bwd t'=-2,-1 garbage
    else      { if (u == 0) c1 = 0.f; }            // fwd t=-1 garbage
    if (!dirv && u >= 1)                           // publish hf1(u-1); keep zeros @u=0
      ((u16*)&hf1l[(par_w * 16 + bM) * 18])[cM] = f16bits(hn1);

    // ---- head partials for t=u-2: fwd uses hf1(u-2) (carry), bwd hb1(u-2) (cur)
    float v = wlM * (dirv ? hn1 : pr);
    pr = hn1;
    v += dppswap8(v);              // sum m-halves (xor 8)
    v += __shfl_xor(v, 16, 64);    // sum q
    v += __shfl_xor(v, 32, 64);
    if (lane < 8) po[par_w * 64 + wv * 8 + lane] = v;

    BARRIER();
    x_cur = x_nxt;
  }
}

__global__ void __launch_bounds__(NT, 2) lstm_kernel(
    const void* __restrict__ xg,
    const void* Wih_f0, const void* Whh_f0, const void* b_f0,
    const void* Wih_f1, const void* Whh_f1, const void* b_f1,
    const void* Wih_b0, const void* Whh_b0, const void* b_b0,
    const void* Wih_b1, const void* Whh_b1, const void* b_b1,
    const void* Wlin, const void* blin, const int* __restrict__ futp,
    void* __restrict__ outp) {
  __shared__ __align__(16) u32 h0s[2 * 2 * 16 * 18];
  __shared__ __align__(16) u32 hf1s[2 * 16 * 18];
  __shared__ __align__(16) float pos_[2 * 64];

  // dtype detection (uniform): bf16-pairs read as fp32 implausible as N(0,1)
  bool bfm;
  {
    const float* xf = (const float*)xg;
    int bad = 0;
    for (int i = 0; i < 64; ++i) {
      float a = fabsf(xf[i]);
      bool ok = (a == 0.0f) || (a > 1e-8f && a < 1e4f);
      if (!ok) bad = 1;
    }
    bfm = (bad != 0);
  }

  if (bfm)
    run<true>(xg, Wih_f0, Whh_f0, b_f0, Wih_f1, Whh_f1, b_f1,
              Wih_b0, Whh_b0, b_b0, Wih_b1, Whh_b1, b_b1,
              Wlin, blin, futp, outp, h0s, hf1s, pos_,
              threadIdx.x, blockIdx.x);
  else
    run<false>(xg, Wih_f0, Whh_f0, b_f0, Wih_f1, Whh_f1, b_f1,
               Wih_b0, Whh_b0, b_b0, Wih_b1, Whh_b1, b_b1,
               Wlin, blin, futp, outp, h0s, hf1s, pos_,
               threadIdx.x, blockIdx.x);
}

extern "C" void kernel_launch(void* const* d_in, const int* in_sizes, int n_in,
                              void* d_out, int out_size, void* d_ws, size_t ws_size,
                              hipStream_t stream) {
  (void)in_sizes; (void)n_in; (void)out_size; (void)d_ws; (void)ws_size;
  lstm_kernel<<<dim3(GRID), dim3(NT), 0, stream>>>(
      d_in[0], d_in[1], d_in[2], d_in[3], d_in[4], d_in[5], d_in[6],
      d_in[7], d_in[8], d_in[9], d_in[10], d_in[11], d_in[12],
      d_in[13], d_in[14], (const int*)d_in[15], d_out);
}